// Round 1
// 1614.617 us; speedup vs baseline: 1.0242x; 1.0242x over previous
//
#include <hip/hip_runtime.h>

typedef _Float16 f16;
typedef _Float16 f16x4 __attribute__((ext_vector_type(4)));
typedef _Float16 f16x8 __attribute__((ext_vector_type(8)));
typedef float f32x4 __attribute__((ext_vector_type(4)));

#define NB   8
#define HW   5476
#define NL   32
#define DIM  1024
#define LIN  768
#define MTOT (NB * HW)            // 43808
#define MTILES ((MTOT + 127) / 128) // 343
#define CSPLIT 128                // colstats row-splits per batch

// ---------------------------------------------------------------- utilities

__device__ __forceinline__ void g2l16(const void* g, void* l) {
#if __has_builtin(__builtin_amdgcn_global_load_lds)
  __builtin_amdgcn_global_load_lds(
      (const __attribute__((address_space(1))) void*)g,
      (__attribute__((address_space(3))) void*)l, 16, 0, 0);
#else
  const int lane = threadIdx.x & 63;
  *(uint4*)((char*)l + lane * 16) = *(const uint4*)g;
#endif
}

__device__ __forceinline__ float gelu_f(float x) {
  return 0.5f * x * (1.0f + erff(x * 0.70710678118654752f));
}

// ---------------------------------------------------------------- big GEMM
// C[M,N] = A[M,K] * W[N,K]^T (+bias, epilogue). K = N = 1024.
// EPI: 0 = gelu->f16, 1 = plain->f16, 2 = plain->f32, 3 = gelu->f32
// EPI2 >= 0: dual-output mode. Blocks with n-tile >= 8 compute A*W2^T with
// epilogue EPI2 into out2 (shares the A panel -> halves A traffic).
// Grid is 1D; XCD-aware bijective swizzle maps each XCD to a contiguous
// chunk of row-tiles (all n-tiles) so A panels stay L2-resident per XCD.
template <int EPI, int EPI2>
__global__ __launch_bounds__(256) void gemm_nt(
    const f16* __restrict__ A, const f16* __restrict__ W,
    const float* __restrict__ bias, void* __restrict__ out,
    const f16* __restrict__ W2, const float* __restrict__ bias2,
    void* __restrict__ out2, int M) {
  constexpr int K = 1024, N = 1024;
  constexpr int NT = (EPI2 >= 0) ? 16 : 8;  // n-tiles per row-tile
  constexpr int NWG = NT * MTILES;          // divisible by 8 (MTILES*NT%8==0)
  constexpr int CHUNK = NWG / 8;
  __shared__ f16 As[128 * 64];  // [m][k], row stride 64 elements (128B)
  __shared__ f16 Bs[128 * 64];  // [n][k]

  // T1: XCD swizzle. Hardware: xcd = linear_bid % 8.
  const int L = blockIdx.x;
  const int w = (L & 7) * CHUNK + (L >> 3);
  const int mt = w / NT;
  int nt = w % NT;
  const f16* Wp = W;
  const float* bp = bias;
  void* op = out;
  bool second = false;
  if constexpr (EPI2 >= 0) {
    if (nt >= 8) {
      nt -= 8;
      Wp = W2;
      bp = bias2;
      op = out2;
      second = true;
    }
  }

  const int tid = threadIdx.x;
  const int wave = tid >> 6, lane = tid & 63;
  const int m0 = mt * 128, n0 = nt * 128;
  const int wm = (wave >> 1) * 64, wn = (wave & 1) * 64;
  const int fr = lane & 15, fq = lane >> 4;

  f32x4 acc[4][4];
#pragma unroll
  for (int i = 0; i < 4; ++i)
#pragma unroll
    for (int j = 0; j < 4; ++j) acc[i][j] = (f32x4){0.f, 0.f, 0.f, 0.f};

  // T2 swizzle: LDS dest is linear (global_load_lds requirement); the source
  // chunk is pre-permuted so that data for (row, chunk c) lands at linear
  // slot c ^ (row&7). Read applies the same involution.
  const int sub = lane >> 3;                  // row within 8-row chunk
  const int scol = ((lane & 7) ^ sub) * 8;    // swizzled source k-chunk

  for (int it = 0; it < K / 64; ++it) {
    const int k0 = it * 64;
#pragma unroll
    for (int i = 0; i < 4; ++i) {
      const int r = wave * 32 + i * 8;
      int gm = m0 + r + sub;
      if (gm > M - 1) gm = M - 1;
      g2l16(A + (size_t)gm * K + k0 + scol, &As[r * 64]);
    }
#pragma unroll
    for (int i = 0; i < 4; ++i) {
      const int r = wave * 32 + i * 8;
      g2l16(Wp + (size_t)(n0 + r + sub) * K + k0 + scol, &Bs[r * 64]);
    }
    __syncthreads();
    const int swz = (fr & 7) << 3;  // element-offset XOR for this lane's rows
#pragma unroll
    for (int kk = 0; kk < 2; ++kk) {
      const int ko = kk * 32 + fq * 8;
      const int kos = ko ^ swz;
      f16x8 af[4], bf[4];
#pragma unroll
      for (int i = 0; i < 4; ++i)
        af[i] = *(const f16x8*)&As[(wm + i * 16 + fr) * 64 + kos];
#pragma unroll
      for (int j = 0; j < 4; ++j)
        bf[j] = *(const f16x8*)&Bs[(wn + j * 16 + fr) * 64 + kos];
#pragma unroll
      for (int i = 0; i < 4; ++i)
#pragma unroll
        for (int j = 0; j < 4; ++j)
          acc[i][j] = __builtin_amdgcn_mfma_f32_16x16x32_f16(af[i], bf[j],
                                                             acc[i][j], 0, 0, 0);
    }
    __syncthreads();
  }

  // Epilogue. C/D layout: col = lane&15, row = (lane>>4)*4 + reg (HW-verified).
  const bool do_gelu = second ? (EPI2 == 0 || EPI2 == 3) : (EPI == 0 || EPI == 3);
  const bool to_f16 = second ? (EPI2 <= 1) : (EPI <= 1);
  const int row0 = m0 + wm + fq * 4;
  const int col0 = n0 + wn + fr;
#pragma unroll
  for (int j = 0; j < 4; ++j) {
    const int col = col0 + j * 16;
    const float bv = bp[col];
#pragma unroll
    for (int i = 0; i < 4; ++i) {
#pragma unroll
      for (int r = 0; r < 4; ++r) {
        const int row = row0 + i * 16 + r;
        if (row < M) {
          float v = acc[i][j][r] + bv;
          if (do_gelu) v = gelu_f(v);
          if (to_f16)
            ((f16*)op)[(size_t)row * N + col] = (f16)v;
          else
            ((float*)op)[(size_t)row * N + col] = v;
        }
      }
    }
  }
}

// ---------------------------------------------------------------- fp32 -> fp16
__global__ void cvt_f32_f16(const float* __restrict__ in, f16* __restrict__ out,
                            int nchunks) {
  const int i = blockIdx.x * 256 + threadIdx.x;
  if (i >= nchunks) return;
  const float4* p = (const float4*)in + (size_t)i * 2;
  const float4 a = p[0], b = p[1];
  f16x8 o = {(f16)a.x, (f16)a.y, (f16)a.z, (f16)a.w,
             (f16)b.x, (f16)b.y, (f16)b.z, (f16)b.w};
  *((f16x8*)out + i) = o;
}

// ---------------------------------------------------------------- column stats
// Two-stage: stage A (coalesced partial sums over row splits), stage B (reduce).
// X is [NB*HW, DIM] row-major. Partials are [CSPLIT, NB, DIM].
template <typename T>
__global__ __launch_bounds__(256) void colstats_partial(
    const T* __restrict__ X, float* __restrict__ psum,
    float* __restrict__ psq) {
  const int b = blockIdx.y;
  const int sp = blockIdx.x;
  const int c = threadIdx.x * 4;  // 4 columns per thread
  constexpr int CHUNK = (HW + CSPLIT - 1) / CSPLIT;  // 43
  const int r0 = sp * CHUNK;
  const int r1 = (r0 + CHUNK < HW) ? r0 + CHUNK : HW;

  float s0 = 0.f, s1 = 0.f, s2 = 0.f, s3 = 0.f;
  float q0 = 0.f, q1 = 0.f, q2 = 0.f, q3 = 0.f;
  const T* base = X + ((size_t)b * HW + r0) * DIM + c;
  for (int r = r0; r < r1; ++r) {
    float v0, v1, v2, v3;
    if constexpr (sizeof(T) == 2) {
      const f16x4 v = *(const f16x4*)base;
      v0 = (float)v[0]; v1 = (float)v[1]; v2 = (float)v[2]; v3 = (float)v[3];
    } else {
      const float4 v = *(const float4*)base;
      v0 = v.x; v1 = v.y; v2 = v.z; v3 = v.w;
    }
    s0 += v0; s1 += v1; s2 += v2; s3 += v3;
    q0 += v0 * v0; q1 += v1 * v1; q2 += v2 * v2; q3 += v3 * v3;
    base += DIM;
  }
  const size_t o = ((size_t)sp * NB + b) * DIM + c;
  *(float4*)&psum[o] = make_float4(s0, s1, s2, s3);
  *(float4*)&psq[o] = make_float4(q0, q1, q2, q3);
}

__global__ __launch_bounds__(256) void colstats_final(
    const float* __restrict__ psum, const float* __restrict__ psq,
    float* __restrict__ mean, float* __restrict__ rinv) {
  const int i = blockIdx.x * 256 + threadIdx.x;  // over NB*DIM = 8192
  float s = 0.f, q = 0.f;
  for (int sp = 0; sp < CSPLIT; ++sp) {
    s += psum[(size_t)sp * NB * DIM + i];
    q += psq[(size_t)sp * NB * DIM + i];
  }
  const float m = s * (1.0f / HW);
  const float var = q * (1.0f / HW) - m * m;
  mean[i] = m;
  rinv[i] = rsqrtf(var + 1e-5f);
}

// ---------------------------------------------------------------- k/v small GEMM
// out[b][o][n] = (sum_c w[o,c]*l[b,n,c] + bias[o]) * mask[b,n]
__global__ __launch_bounds__(256) void kv_gemm(
    const float* __restrict__ l, const float* __restrict__ lmask,
    const float* __restrict__ wk, const float* __restrict__ bk,
    const float* __restrict__ wv, const float* __restrict__ bv,
    float* __restrict__ Kout, float* __restrict__ Vout) {
  const int b = blockIdx.z;
  const int o0 = blockIdx.x * 64;
  const float* w = blockIdx.y ? wv : wk;
  const float* bb = blockIdx.y ? bv : bk;
  float* out = blockIdx.y ? Vout : Kout;

  __shared__ float wl[64 * 129];
  __shared__ float ll[32 * 129];
  const int tid = threadIdx.x;
  const int o = tid & 63, ng = tid >> 6;  // each thread: 1 o x 8 n
  float acc[8];
#pragma unroll
  for (int j = 0; j < 8; ++j) acc[j] = 0.f;

  for (int kc = 0; kc < LIN; kc += 128) {
    for (int e = tid; e < 64 * 128; e += 256)
      wl[(e >> 7) * 129 + (e & 127)] =
          w[(size_t)(o0 + (e >> 7)) * LIN + kc + (e & 127)];
    for (int e = tid; e < 32 * 128; e += 256)
      ll[(e >> 7) * 129 + (e & 127)] =
          l[(size_t)b * NL * LIN + (size_t)(e >> 7) * LIN + kc + (e & 127)];
    __syncthreads();
    for (int k = 0; k < 128; ++k) {
      const float wv_ = wl[o * 129 + k];
#pragma unroll
      for (int j = 0; j < 8; ++j) acc[j] += wv_ * ll[(ng * 8 + j) * 129 + k];
    }
    __syncthreads();
  }
  const float bval = bb[o0 + o];
#pragma unroll
  for (int j = 0; j < 8; ++j) {
    const int n = ng * 8 + j;
    out[((size_t)b * DIM + o0 + o) * NL + n] =
        (acc[j] + bval) * lmask[b * NL + n];
  }
}

// ---------------------------------------------------------------- attention
// Per (b,h,m): scores over 32 keys (dk=128), softmax, weighted sum of v (dv=128).
__global__ __launch_bounds__(256) void attn_kernel(
    const f16* __restrict__ Q, const float* __restrict__ qmean,
    const float* __restrict__ qrinv, const float* __restrict__ Kk,
    const float* __restrict__ Vv, const float* __restrict__ lmask,
    float* __restrict__ Out) {
  const int b = blockIdx.z, h = blockIdx.y;
  __shared__ float ks[128 * NL], vs[128 * NL], qm[128], qr[128], bs[NL];
  const int tid = threadIdx.x;
  const float* kbase = Kk + ((size_t)b * DIM + h * 128) * NL;
  const float* vbase = Vv + ((size_t)b * DIM + h * 128) * NL;
  for (int i = tid; i < 128 * NL; i += 256) {
    ks[i] = kbase[i];
    vs[i] = vbase[i];
  }
  if (tid < 128) {
    qm[tid] = qmean[b * DIM + h * 128 + tid];
    qr[tid] = qrinv[b * DIM + h * 128 + tid];
  }
  if (tid < NL) bs[tid] = (lmask[b * NL + tid] - 1.0f) * 10000.0f;
  __syncthreads();

  const int mloc = blockIdx.x * 256 + tid;
  if (mloc >= HW) return;
  const size_t m = (size_t)b * HW + mloc;
  const f16* qrow = Q + m * DIM + h * 128;

  float sc[32];
#pragma unroll
  for (int n = 0; n < 32; ++n) sc[n] = 0.f;

  for (int d8 = 0; d8 < 16; ++d8) {
    const f16x8 qv = *(const f16x8*)(qrow + d8 * 8);
#pragma unroll
    for (int j = 0; j < 8; ++j) {
      const int d = d8 * 8 + j;
      const float qd = ((float)qv[j] - qm[d]) * qr[d];
      const float4* kr = (const float4*)&ks[d * 32];
#pragma unroll
      for (int n4 = 0; n4 < 8; ++n4) {
        const float4 kk = kr[n4];
        sc[n4 * 4 + 0] += qd * kk.x;
        sc[n4 * 4 + 1] += qd * kk.y;
        sc[n4 * 4 + 2] += qd * kk.z;
        sc[n4 * 4 + 3] += qd * kk.w;
      }
    }
  }
  float mx = -1e30f;
#pragma unroll
  for (int n = 0; n < 32; ++n) {
    sc[n] = sc[n] * 0.03125f + bs[n];  // * KC^-0.5 then masked bias
    mx = fmaxf(mx, sc[n]);
  }
  float sum = 0.f;
#pragma unroll
  for (int n = 0; n < 32; ++n) {
    sc[n] = __expf(sc[n] - mx);
    sum += sc[n];
  }
  const float rs = 1.0f / sum;

  float* orow = Out + m * DIM + h * 128;
  for (int dv8 = 0; dv8 < 16; ++dv8) {
    float ov[8];
#pragma unroll
    for (int j = 0; j < 8; ++j) {
      const float4* vr = (const float4*)&vs[(dv8 * 8 + j) * 32];
      float a = 0.f;
#pragma unroll
      for (int n4 = 0; n4 < 8; ++n4) {
        const float4 vv = vr[n4];
        a += sc[n4 * 4 + 0] * vv.x + sc[n4 * 4 + 1] * vv.y +
             sc[n4 * 4 + 2] * vv.z + sc[n4 * 4 + 3] * vv.w;
      }
      ov[j] = a * rs;
    }
    float4* op = (float4*)(orow + dv8 * 8);
    op[0] = make_float4(ov[0], ov[1], ov[2], ov[3]);
    op[1] = make_float4(ov[4], ov[5], ov[6], ov[7]);
  }
}

// ---------------------------------------------------------------- center (attn - colmean) -> f16
__global__ void center_kernel(const float* __restrict__ X,
                              const float* __restrict__ mean,
                              f16* __restrict__ out, int nchunks) {
  const int i = blockIdx.x * 256 + threadIdx.x;
  if (i >= nchunks) return;
  const size_t e = (size_t)i * 8;
  const int mrow = (int)(e >> 10);
  const int o = (int)(e & 1023);
  const int b = mrow / HW;
  const float4* p = (const float4*)(X + e);
  const float4 a = p[0], c = p[1];
  const float* mn = mean + b * DIM + o;
  f16x8 r = {(f16)(a.x - mn[0]), (f16)(a.y - mn[1]), (f16)(a.z - mn[2]),
             (f16)(a.w - mn[3]), (f16)(c.x - mn[4]), (f16)(c.y - mn[5]),
             (f16)(c.z - mn[6]), (f16)(c.w - mn[7])};
  *((f16x8*)out + i) = r;
}

// ---------------------------------------------------------------- fuse: mm = vis * inorm(lang_pre)
__global__ void fuse_kernel(const f16* __restrict__ vis,
                            const float* __restrict__ lang,
                            const float* __restrict__ mean,
                            const float* __restrict__ rinv,
                            f16* __restrict__ out, int nchunks) {
  const int i = blockIdx.x * 256 + threadIdx.x;
  if (i >= nchunks) return;
  const size_t e = (size_t)i * 8;
  const int mrow = (int)(e >> 10);
  const int o = (int)(e & 1023);
  const int b = mrow / HW;
  const f16x8 v = *((const f16x8*)vis + i);
  const float4* p = (const float4*)(lang + e);
  const float4 a = p[0], c = p[1];
  const float lv[8] = {a.x, a.y, a.z, a.w, c.x, c.y, c.z, c.w};
  const float* mn = mean + b * DIM + o;
  const float* ri = rinv + b * DIM + o;
  f16x8 r;
#pragma unroll
  for (int j = 0; j < 8; ++j)
    r[j] = (f16)((float)v[j] * ((lv[j] - mn[j]) * ri[j]));
  *((f16x8*)out + i) = r;
}

// ---------------------------------------------------------------- launch
extern "C" void kernel_launch(void* const* d_in, const int* in_sizes, int n_in,
                              void* d_out, int out_size, void* d_ws,
                              size_t ws_size, hipStream_t stream) {
  const float* x     = (const float*)d_in[0];
  const float* l     = (const float*)d_in[1];
  const float* lmask = (const float*)d_in[2];
  const float* vis_w = (const float*)d_in[3];
  const float* vis_b = (const float*)d_in[4];
  const float* fq_w  = (const float*)d_in[5];
  const float* fq_b  = (const float*)d_in[6];
  const float* fk_w  = (const float*)d_in[7];
  const float* fk_b  = (const float*)d_in[8];
  const float* fv_w  = (const float*)d_in[9];
  const float* fv_b  = (const float*)d_in[10];
  const float* W_w   = (const float*)d_in[11];
  const float* W_b   = (const float*)d_in[12];
  const float* pm_w  = (const float*)d_in[13];
  const float* pm_b  = (const float*)d_in[14];

  char* ws = (char*)d_ws;
  const size_t SB = (size_t)MTOT * DIM * 2;  // one f16 [M,1024] buffer
  f16* Ah = (f16*)(ws);                      // x_f16 -> centered attn -> mm
  f16* Bh = (f16*)(ws + SB);                 // vis
  f16* Ch = (f16*)(ws + 2 * SB);             // q (f16)
  float* Df = (float*)(ws + 3 * SB);         // attn f32 -> lang_pre f32 (2*SB bytes)
  char* wsp = ws + 5 * SB;
  f16* vis_wh = (f16*)(wsp);
  f16* fq_wh  = (f16*)(wsp + (1 << 21));
  f16* W_wh   = (f16*)(wsp + 2 * (1 << 21));
  f16* pm_wh  = (f16*)(wsp + 3 * (1 << 21));
  float* Kout = (float*)(wsp + 4 * (1 << 21));
  float* Vout = (float*)(wsp + 4 * (1 << 21) + (1 << 20));
  float* st   = (float*)(wsp + 4 * (1 << 21) + 2 * (1 << 20));
  float* qmean = st;
  float* qrinv = st + 8192;
  float* amean = st + 16384;
  float* arinv = st + 24576;
  float* lmean = st + 32768;
  float* lrinv = st + 40960;
  float* psum  = (float*)(wsp + 4 * (1 << 21) + 3 * (1 << 20));  // CSPLIT*NB*DIM
  float* psq   = psum + (size_t)CSPLIT * NB * DIM;

  const int NCH_BIG = MTOT * DIM / 8;  // 5,607,424 chunks of 8
  const int NCH_W = DIM * DIM / 8;     // 131,072

  cvt_f32_f16<<<(NCH_BIG + 255) / 256, 256, 0, stream>>>(x, Ah, NCH_BIG);
  cvt_f32_f16<<<(NCH_W + 255) / 256, 256, 0, stream>>>(vis_w, vis_wh, NCH_W);
  cvt_f32_f16<<<(NCH_W + 255) / 256, 256, 0, stream>>>(fq_w, fq_wh, NCH_W);
  cvt_f32_f16<<<(NCH_W + 255) / 256, 256, 0, stream>>>(W_w, W_wh, NCH_W);
  cvt_f32_f16<<<(NCH_W + 255) / 256, 256, 0, stream>>>(pm_w, pm_wh, NCH_W);

  kv_gemm<<<dim3(16, 2, 8), 256, 0, stream>>>(l, lmask, fk_w, fk_b, fv_w, fv_b,
                                              Kout, Vout);

  // vis + q fused: one pass over A, 16 n-tiles (8 vis/gelu, 8 fq/plain).
  gemm_nt<0, 1><<<16 * MTILES, 256, 0, stream>>>(
      Ah, vis_wh, vis_b, Bh, fq_wh, fq_b, Ch, MTOT);

  colstats_partial<f16><<<dim3(CSPLIT, NB), 256, 0, stream>>>(Ch, psum, psq);
  colstats_final<<<32, 256, 0, stream>>>(psum, psq, qmean, qrinv);

  attn_kernel<<<dim3((HW + 255) / 256, 8, 8), 256, 0, stream>>>(
      Ch, qmean, qrinv, Kout, Vout, lmask, Df);

  colstats_partial<float><<<dim3(CSPLIT, NB), 256, 0, stream>>>(Df, psum, psq);
  colstats_final<<<32, 256, 0, stream>>>(psum, psq, amean, arinv);
  center_kernel<<<(NCH_BIG + 255) / 256, 256, 0, stream>>>(Df, amean, Ah,
                                                           NCH_BIG);

  gemm_nt<2, -1><<<8 * MTILES, 256, 0, stream>>>(
      Ah, W_wh, W_b, Df, nullptr, nullptr, nullptr, MTOT);  // lang_pre f32
  colstats_partial<float><<<dim3(CSPLIT, NB), 256, 0, stream>>>(Df, psum, psq);
  colstats_final<<<32, 256, 0, stream>>>(psum, psq, lmean, lrinv);
  fuse_kernel<<<(NCH_BIG + 255) / 256, 256, 0, stream>>>(Bh, Df, lmean, lrinv,
                                                         Ah, NCH_BIG);

  gemm_nt<3, -1><<<8 * MTILES, 256, 0, stream>>>(
      Ah, pm_wh, pm_b, d_out, nullptr, nullptr, nullptr, MTOT);  // output
}

// Round 2
// 1448.696 us; speedup vs baseline: 1.1415x; 1.1145x over previous
//
#include <hip/hip_runtime.h>

typedef _Float16 f16;
typedef _Float16 f16x4 __attribute__((ext_vector_type(4)));
typedef _Float16 f16x8 __attribute__((ext_vector_type(8)));
typedef float f32x4 __attribute__((ext_vector_type(4)));

#define NB   8
#define HW   5476
#define NL   32
#define DIM  1024
#define LIN  768
#define MTOT (NB * HW)            // 43808
#define MT256 ((MTOT + 255) / 256)  // 172 row-tiles of 256
#define CSPLIT 128                // colstats row-splits per batch

// ---------------------------------------------------------------- utilities

__device__ __forceinline__ void g2l16(const void* g, void* l) {
#if __has_builtin(__builtin_amdgcn_global_load_lds)
  __builtin_amdgcn_global_load_lds(
      (const __attribute__((address_space(1))) void*)g,
      (__attribute__((address_space(3))) void*)l, 16, 0, 0);
#else
  const int lane = threadIdx.x & 63;
  *(uint4*)((char*)l + lane * 16) = *(const uint4*)g;
#endif
}

__device__ __forceinline__ float gelu_f(float x) {
  return 0.5f * x * (1.0f + erff(x * 0.70710678118654752f));
}

// ---------------------------------------------------------------- big GEMM
// C[M,N] = A[M,K] * W[N,K]^T (+bias, epilogue). K = N = 1024.
// 256x256 tile, BK=64, 8 waves (2M x 4N), double-buffered LDS (128 KiB),
// counted vmcnt (T4): next tile's global_load_lds issued BEFORE compute,
// waited with vmcnt(8) after -> HBM latency hides under 64 MFMAs.
// EPI: 0 = gelu->f16, 1 = plain->f16, 2 = plain->f32, 3 = gelu->f32
// EPI2 >= 0: dual-output mode; blocks with nt >= 4 use W2/bias2/out2.
// T1: bijective XCD swizzle, mt-contiguous chunks, nt fastest (A L2 reuse).
// T2: LDS XOR swizzle via pre-swizzled global source + swizzled read.
template <int EPI, int EPI2>
__global__ __launch_bounds__(512, 2) void gemm256(
    const f16* __restrict__ A, const f16* __restrict__ W,
    const float* __restrict__ bias, void* __restrict__ out,
    const f16* __restrict__ W2, const float* __restrict__ bias2,
    void* __restrict__ out2, int M) {
  constexpr int K = 1024, N = 1024;
  constexpr int NT = (EPI2 >= 0) ? 8 : 4;  // 256-col tiles (dual: 4 + 4)
  constexpr int NWG = NT * MT256;          // 1376 or 688, both % 8 == 0
  constexpr int CHUNK = NWG / 8;
  __shared__ f16 lds[2][2][256 * 64];  // [buf][A=0/B=1][row*64 + k]

  // T1: xcd = blockIdx.x % 8 (hardware round-robin).
  const int L = blockIdx.x;
  const int w = (L & 7) * CHUNK + (L >> 3);
  const int mt = w / NT;
  int nt = w % NT;
  const f16* Wp = W;
  const float* bp = bias;
  void* op = out;
  bool second = false;
  if constexpr (EPI2 >= 0) {
    if (nt >= 4) {
      nt -= 4;
      Wp = W2;
      bp = bias2;
      op = out2;
      second = true;
    }
  }

  const int tid = threadIdx.x;
  const int wave = tid >> 6, lane = tid & 63;
  const int m0 = mt * 256, n0 = nt * 256;
  const int wm = (wave >> 2) * 128;  // 2 waves in M
  const int wn = (wave & 3) * 64;    // 4 waves in N
  const int fr = lane & 15, fq = lane >> 4;

  f32x4 acc[8][4];
#pragma unroll
  for (int i = 0; i < 8; ++i)
#pragma unroll
    for (int j = 0; j < 4; ++j) acc[i][j] = (f32x4){0.f, 0.f, 0.f, 0.f};

  // T2: source pre-swizzle. LDS slot (lane&7) of row sub holds global
  // k-chunk (lane&7)^sub; read applies the same XOR.
  const int sub = lane >> 3;
  const int scol = ((lane & 7) ^ sub) * 8;

  const f16* Abase = A + (size_t)0;

  // stage one K-tile (256 rows A + 256 rows B, 8 g2l16/thread)
  auto stage = [&](int buf, int k0) {
#pragma unroll
    for (int i = 0; i < 4; ++i) {
      const int r = wave * 32 + i * 8;
      int gm = m0 + r + sub;
      if (gm > M - 1) gm = M - 1;
      g2l16(Abase + (size_t)gm * K + k0 + scol, &lds[buf][0][r * 64]);
    }
#pragma unroll
    for (int i = 0; i < 4; ++i) {
      const int r = wave * 32 + i * 8;
      g2l16(Wp + (size_t)(n0 + r + sub) * K + k0 + scol, &lds[buf][1][r * 64]);
    }
  };

  stage(0, 0);
  for (int it = 0; it < K / 64; ++it) {
    const int cur = it & 1;
    if (it < K / 64 - 1) {
      stage(cur ^ 1, (it + 1) * 64);
      asm volatile("s_waitcnt vmcnt(8)" ::: "memory");  // cur's 8 loads done
    } else {
      asm volatile("s_waitcnt vmcnt(0)" ::: "memory");
    }
    asm volatile("s_barrier" ::: "memory");

#pragma unroll
    for (int ks = 0; ks < 2; ++ks) {
      const int ko = ks * 32 + fq * 8;
      const int kos = ko ^ ((fr & 7) << 3);
      f16x8 af[8], bf[4];
#pragma unroll
      for (int i = 0; i < 8; ++i)
        af[i] = *(const f16x8*)&lds[cur][0][(wm + i * 16 + fr) * 64 + kos];
#pragma unroll
      for (int j = 0; j < 4; ++j)
        bf[j] = *(const f16x8*)&lds[cur][1][(wn + j * 16 + fr) * 64 + kos];
#pragma unroll
      for (int i = 0; i < 8; ++i)
#pragma unroll
        for (int j = 0; j < 4; ++j)
          acc[i][j] = __builtin_amdgcn_mfma_f32_16x16x32_f16(af[i], bf[j],
                                                             acc[i][j], 0, 0, 0);
    }
    asm volatile("s_waitcnt lgkmcnt(0)" ::: "memory");  // LDS reads retired
    asm volatile("s_barrier" ::: "memory");             // before overwrite
  }

  // Epilogue. C/D layout: col = lane&15, row = (lane>>4)*4 + reg.
  const bool do_gelu = second ? (EPI2 == 0 || EPI2 == 3) : (EPI == 0 || EPI == 3);
  const bool to_f16 = second ? (EPI2 <= 1) : (EPI <= 1);
  const int row0 = m0 + wm + fq * 4;
  const int col0 = n0 + wn + fr;
#pragma unroll
  for (int j = 0; j < 4; ++j) {
    const int col = col0 + j * 16;
    const float bv = bp[col];
#pragma unroll
    for (int i = 0; i < 8; ++i) {
#pragma unroll
      for (int r = 0; r < 4; ++r) {
        const int row = row0 + i * 16 + r;
        if (row < M) {
          float v = acc[i][j][r] + bv;
          if (do_gelu) v = gelu_f(v);
          if (to_f16)
            ((f16*)op)[(size_t)row * N + col] = (f16)v;
          else
            ((float*)op)[(size_t)row * N + col] = v;
        }
      }
    }
  }
}

// ---------------------------------------------------------------- fp32 -> fp16
__global__ void cvt_f32_f16(const float* __restrict__ in, f16* __restrict__ out,
                            int nchunks) {
  const int i = blockIdx.x * 256 + threadIdx.x;
  if (i >= nchunks) return;
  const float4* p = (const float4*)in + (size_t)i * 2;
  const float4 a = p[0], b = p[1];
  f16x8 o = {(f16)a.x, (f16)a.y, (f16)a.z, (f16)a.w,
             (f16)b.x, (f16)b.y, (f16)b.z, (f16)b.w};
  *((f16x8*)out + i) = o;
}

// ---------------------------------------------------------------- column stats
template <typename T>
__global__ __launch_bounds__(256) void colstats_partial(
    const T* __restrict__ X, float* __restrict__ psum,
    float* __restrict__ psq) {
  const int b = blockIdx.y;
  const int sp = blockIdx.x;
  const int c = threadIdx.x * 4;  // 4 columns per thread
  constexpr int CHUNK = (HW + CSPLIT - 1) / CSPLIT;  // 43
  const int r0 = sp * CHUNK;
  const int r1 = (r0 + CHUNK < HW) ? r0 + CHUNK : HW;

  float s0 = 0.f, s1 = 0.f, s2 = 0.f, s3 = 0.f;
  float q0 = 0.f, q1 = 0.f, q2 = 0.f, q3 = 0.f;
  const T* base = X + ((size_t)b * HW + r0) * DIM + c;
  for (int r = r0; r < r1; ++r) {
    float v0, v1, v2, v3;
    if constexpr (sizeof(T) == 2) {
      const f16x4 v = *(const f16x4*)base;
      v0 = (float)v[0]; v1 = (float)v[1]; v2 = (float)v[2]; v3 = (float)v[3];
    } else {
      const float4 v = *(const float4*)base;
      v0 = v.x; v1 = v.y; v2 = v.z; v3 = v.w;
    }
    s0 += v0; s1 += v1; s2 += v2; s3 += v3;
    q0 += v0 * v0; q1 += v1 * v1; q2 += v2 * v2; q3 += v3 * v3;
    base += DIM;
  }
  const size_t o = ((size_t)sp * NB + b) * DIM + c;
  *(float4*)&psum[o] = make_float4(s0, s1, s2, s3);
  *(float4*)&psq[o] = make_float4(q0, q1, q2, q3);
}

__global__ __launch_bounds__(256) void colstats_final(
    const float* __restrict__ psum, const float* __restrict__ psq,
    float* __restrict__ mean, float* __restrict__ rinv) {
  const int i = blockIdx.x * 256 + threadIdx.x;  // over NB*DIM = 8192
  float s = 0.f, q = 0.f;
  for (int sp = 0; sp < CSPLIT; ++sp) {
    s += psum[(size_t)sp * NB * DIM + i];
    q += psq[(size_t)sp * NB * DIM + i];
  }
  const float m = s * (1.0f / HW);
  const float var = q * (1.0f / HW) - m * m;
  mean[i] = m;
  rinv[i] = rsqrtf(var + 1e-5f);
}

// ---------------------------------------------------------------- k/v small GEMM
__global__ __launch_bounds__(256) void kv_gemm(
    const float* __restrict__ l, const float* __restrict__ lmask,
    const float* __restrict__ wk, const float* __restrict__ bk,
    const float* __restrict__ wv, const float* __restrict__ bv,
    float* __restrict__ Kout, float* __restrict__ Vout) {
  const int b = blockIdx.z;
  const int o0 = blockIdx.x * 64;
  const float* w = blockIdx.y ? wv : wk;
  const float* bb = blockIdx.y ? bv : bk;
  float* out = blockIdx.y ? Vout : Kout;

  __shared__ float wl[64 * 129];
  __shared__ float ll[32 * 129];
  const int tid = threadIdx.x;
  const int o = tid & 63, ng = tid >> 6;  // each thread: 1 o x 8 n
  float acc[8];
#pragma unroll
  for (int j = 0; j < 8; ++j) acc[j] = 0.f;

  for (int kc = 0; kc < LIN; kc += 128) {
    for (int e = tid; e < 64 * 128; e += 256)
      wl[(e >> 7) * 129 + (e & 127)] =
          w[(size_t)(o0 + (e >> 7)) * LIN + kc + (e & 127)];
    for (int e = tid; e < 32 * 128; e += 256)
      ll[(e >> 7) * 129 + (e & 127)] =
          l[(size_t)b * NL * LIN + (size_t)(e >> 7) * LIN + kc + (e & 127)];
    __syncthreads();
    for (int k = 0; k < 128; ++k) {
      const float wv_ = wl[o * 129 + k];
#pragma unroll
      for (int j = 0; j < 8; ++j) acc[j] += wv_ * ll[(ng * 8 + j) * 129 + k];
    }
    __syncthreads();
  }
  const float bval = bb[o0 + o];
#pragma unroll
  for (int j = 0; j < 8; ++j) {
    const int n = ng * 8 + j;
    out[((size_t)b * DIM + o0 + o) * NL + n] =
        (acc[j] + bval) * lmask[b * NL + n];
  }
}

// ---------------------------------------------------------------- attention
__global__ __launch_bounds__(256) void attn_kernel(
    const f16* __restrict__ Q, const float* __restrict__ qmean,
    const float* __restrict__ qrinv, const float* __restrict__ Kk,
    const float* __restrict__ Vv, const float* __restrict__ lmask,
    float* __restrict__ Out) {
  const int b = blockIdx.z, h = blockIdx.y;
  __shared__ float ks[128 * NL], vs[128 * NL], qm[128], qr[128], bs[NL];
  const int tid = threadIdx.x;
  const float* kbase = Kk + ((size_t)b * DIM + h * 128) * NL;
  const float* vbase = Vv + ((size_t)b * DIM + h * 128) * NL;
  for (int i = tid; i < 128 * NL; i += 256) {
    ks[i] = kbase[i];
    vs[i] = vbase[i];
  }
  if (tid < 128) {
    qm[tid] = qmean[b * DIM + h * 128 + tid];
    qr[tid] = qrinv[b * DIM + h * 128 + tid];
  }
  if (tid < NL) bs[tid] = (lmask[b * NL + tid] - 1.0f) * 10000.0f;
  __syncthreads();

  const int mloc = blockIdx.x * 256 + tid;
  if (mloc >= HW) return;
  const size_t m = (size_t)b * HW + mloc;
  const f16* qrow = Q + m * DIM + h * 128;

  float sc[32];
#pragma unroll
  for (int n = 0; n < 32; ++n) sc[n] = 0.f;

  for (int d8 = 0; d8 < 16; ++d8) {
    const f16x8 qv = *(const f16x8*)(qrow + d8 * 8);
#pragma unroll
    for (int j = 0; j < 8; ++j) {
      const int d = d8 * 8 + j;
      const float qd = ((float)qv[j] - qm[d]) * qr[d];
      const float4* kr = (const float4*)&ks[d * 32];
#pragma unroll
      for (int n4 = 0; n4 < 8; ++n4) {
        const float4 kk = kr[n4];
        sc[n4 * 4 + 0] += qd * kk.x;
        sc[n4 * 4 + 1] += qd * kk.y;
        sc[n4 * 4 + 2] += qd * kk.z;
        sc[n4 * 4 + 3] += qd * kk.w;
      }
    }
  }
  float mx = -1e30f;
#pragma unroll
  for (int n = 0; n < 32; ++n) {
    sc[n] = sc[n] * 0.03125f + bs[n];  // * KC^-0.5 then masked bias
    mx = fmaxf(mx, sc[n]);
  }
  float sum = 0.f;
#pragma unroll
  for (int n = 0; n < 32; ++n) {
    sc[n] = __expf(sc[n] - mx);
    sum += sc[n];
  }
  const float rs = 1.0f / sum;

  float* orow = Out + m * DIM + h * 128;
  for (int dv8 = 0; dv8 < 16; ++dv8) {
    float ov[8];
#pragma unroll
    for (int j = 0; j < 8; ++j) {
      const float4* vr = (const float4*)&vs[(dv8 * 8 + j) * 32];
      float a = 0.f;
#pragma unroll
      for (int n4 = 0; n4 < 8; ++n4) {
        const float4 vv = vr[n4];
        a += sc[n4 * 4 + 0] * vv.x + sc[n4 * 4 + 1] * vv.y +
             sc[n4 * 4 + 2] * vv.z + sc[n4 * 4 + 3] * vv.w;
      }
      ov[j] = a * rs;
    }
    float4* op = (float4*)(orow + dv8 * 8);
    op[0] = make_float4(ov[0], ov[1], ov[2], ov[3]);
    op[1] = make_float4(ov[4], ov[5], ov[6], ov[7]);
  }
}

// ---------------------------------------------------------------- center (attn - colmean) -> f16
__global__ void center_kernel(const float* __restrict__ X,
                              const float* __restrict__ mean,
                              f16* __restrict__ out, int nchunks) {
  const int i = blockIdx.x * 256 + threadIdx.x;
  if (i >= nchunks) return;
  const size_t e = (size_t)i * 8;
  const int mrow = (int)(e >> 10);
  const int o = (int)(e & 1023);
  const int b = mrow / HW;
  const float4* p = (const float4*)(X + e);
  const float4 a = p[0], c = p[1];
  const float* mn = mean + b * DIM + o;
  f16x8 r = {(f16)(a.x - mn[0]), (f16)(a.y - mn[1]), (f16)(a.z - mn[2]),
             (f16)(a.w - mn[3]), (f16)(c.x - mn[4]), (f16)(c.y - mn[5]),
             (f16)(c.z - mn[6]), (f16)(c.w - mn[7])};
  *((f16x8*)out + i) = r;
}

// ---------------------------------------------------------------- fuse: mm = vis * inorm(lang_pre)
__global__ void fuse_kernel(const f16* __restrict__ vis,
                            const float* __restrict__ lang,
                            const float* __restrict__ mean,
                            const float* __restrict__ rinv,
                            f16* __restrict__ out, int nchunks) {
  const int i = blockIdx.x * 256 + threadIdx.x;
  if (i >= nchunks) return;
  const size_t e = (size_t)i * 8;
  const int mrow = (int)(e >> 10);
  const int o = (int)(e & 1023);
  const int b = mrow / HW;
  const f16x8 v = *((const f16x8*)vis + i);
  const float4* p = (const float4*)(lang + e);
  const float4 a = p[0], c = p[1];
  const float lv[8] = {a.x, a.y, a.z, a.w, c.x, c.y, c.z, c.w};
  const float* mn = mean + b * DIM + o;
  const float* ri = rinv + b * DIM + o;
  f16x8 r;
#pragma unroll
  for (int j = 0; j < 8; ++j)
    r[j] = (f16)((float)v[j] * ((lv[j] - mn[j]) * ri[j]));
  *((f16x8*)out + i) = r;
}

// ---------------------------------------------------------------- launch
extern "C" void kernel_launch(void* const* d_in, const int* in_sizes, int n_in,
                              void* d_out, int out_size, void* d_ws,
                              size_t ws_size, hipStream_t stream) {
  const float* x     = (const float*)d_in[0];
  const float* l     = (const float*)d_in[1];
  const float* lmask = (const float*)d_in[2];
  const float* vis_w = (const float*)d_in[3];
  const float* vis_b = (const float*)d_in[4];
  const float* fq_w  = (const float*)d_in[5];
  const float* fq_b  = (const float*)d_in[6];
  const float* fk_w  = (const float*)d_in[7];
  const float* fk_b  = (const float*)d_in[8];
  const float* fv_w  = (const float*)d_in[9];
  const float* fv_b  = (const float*)d_in[10];
  const float* W_w   = (const float*)d_in[11];
  const float* W_b   = (const float*)d_in[12];
  const float* pm_w  = (const float*)d_in[13];
  const float* pm_b  = (const float*)d_in[14];

  char* ws = (char*)d_ws;
  const size_t SB = (size_t)MTOT * DIM * 2;  // one f16 [M,1024] buffer
  f16* Ah = (f16*)(ws);                      // x_f16 -> centered attn -> mm
  f16* Bh = (f16*)(ws + SB);                 // vis
  f16* Ch = (f16*)(ws + 2 * SB);             // q (f16)
  float* Df = (float*)(ws + 3 * SB);         // attn f32 -> lang_pre f32 (2*SB bytes)
  char* wsp = ws + 5 * SB;
  f16* vis_wh = (f16*)(wsp);
  f16* fq_wh  = (f16*)(wsp + (1 << 21));
  f16* W_wh   = (f16*)(wsp + 2 * (1 << 21));
  f16* pm_wh  = (f16*)(wsp + 3 * (1 << 21));
  float* Kout = (float*)(wsp + 4 * (1 << 21));
  float* Vout = (float*)(wsp + 4 * (1 << 21) + (1 << 20));
  float* st   = (float*)(wsp + 4 * (1 << 21) + 2 * (1 << 20));
  float* qmean = st;
  float* qrinv = st + 8192;
  float* amean = st + 16384;
  float* arinv = st + 24576;
  float* lmean = st + 32768;
  float* lrinv = st + 40960;
  float* psum  = (float*)(wsp + 4 * (1 << 21) + 3 * (1 << 20));  // CSPLIT*NB*DIM
  float* psq   = psum + (size_t)CSPLIT * NB * DIM;

  const int NCH_BIG = MTOT * DIM / 8;  // 5,607,424 chunks of 8
  const int NCH_W = DIM * DIM / 8;     // 131,072

  cvt_f32_f16<<<(NCH_BIG + 255) / 256, 256, 0, stream>>>(x, Ah, NCH_BIG);
  cvt_f32_f16<<<(NCH_W + 255) / 256, 256, 0, stream>>>(vis_w, vis_wh, NCH_W);
  cvt_f32_f16<<<(NCH_W + 255) / 256, 256, 0, stream>>>(fq_w, fq_wh, NCH_W);
  cvt_f32_f16<<<(NCH_W + 255) / 256, 256, 0, stream>>>(W_w, W_wh, NCH_W);
  cvt_f32_f16<<<(NCH_W + 255) / 256, 256, 0, stream>>>(pm_w, pm_wh, NCH_W);

  kv_gemm<<<dim3(16, 2, 8), 256, 0, stream>>>(l, lmask, fk_w, fk_b, fv_w, fv_b,
                                              Kout, Vout);

  // vis + q fused: one pass over A, 8 col-tiles (4 vis/gelu, 4 fq/plain).
  gemm256<0, 1><<<8 * MT256, 512, 0, stream>>>(
      Ah, vis_wh, vis_b, Bh, fq_wh, fq_b, Ch, MTOT);

  colstats_partial<f16><<<dim3(CSPLIT, NB), 256, 0, stream>>>(Ch, psum, psq);
  colstats_final<<<32, 256, 0, stream>>>(psum, psq, qmean, qrinv);

  attn_kernel<<<dim3((HW + 255) / 256, 8, 8), 256, 0, stream>>>(
      Ch, qmean, qrinv, Kout, Vout, lmask, Df);

  colstats_partial<float><<<dim3(CSPLIT, NB), 256, 0, stream>>>(Df, psum, psq);
  colstats_final<<<32, 256, 0, stream>>>(psum, psq, amean, arinv);
  center_kernel<<<(NCH_BIG + 255) / 256, 256, 0, stream>>>(Df, amean, Ah,
                                                           NCH_BIG);

  gemm256<2, -1><<<4 * MT256, 512, 0, stream>>>(
      Ah, W_wh, W_b, Df, nullptr, nullptr, nullptr, MTOT);  // lang_pre f32
  colstats_partial<float><<<dim3(CSPLIT, NB), 256, 0, stream>>>(Df, psum, psq);
  colstats_final<<<32, 256, 0, stream>>>(psum, psq, lmean, lrinv);
  fuse_kernel<<<(NCH_BIG + 255) / 256, 256, 0, stream>>>(Bh, Df, lmean, lrinv,
                                                         Ah, NCH_BIG);

  gemm256<3, -1><<<4 * MT256, 512, 0, stream>>>(
      Ah, pm_wh, pm_b, d_out, nullptr, nullptr, nullptr, MTOT);  // output
}

// Round 3
// 1438.931 us; speedup vs baseline: 1.1492x; 1.0068x over previous
//
#include <hip/hip_runtime.h>

typedef _Float16 f16;
typedef _Float16 f16x4 __attribute__((ext_vector_type(4)));
typedef _Float16 f16x8 __attribute__((ext_vector_type(8)));
typedef float f32x4 __attribute__((ext_vector_type(4)));

#define NB   8
#define HW   5476
#define NL   32
#define DIM  1024
#define LIN  768
#define MTOT (NB * HW)            // 43808
#define MT256 ((MTOT + 255) / 256)  // 172 row-tiles of 256
#define CSPLIT 128                // colstats row-splits per batch

// ---------------------------------------------------------------- utilities

__device__ __forceinline__ void g2l16(const void* g, void* l) {
#if __has_builtin(__builtin_amdgcn_global_load_lds)
  __builtin_amdgcn_global_load_lds(
      (const __attribute__((address_space(1))) void*)g,
      (__attribute__((address_space(3))) void*)l, 16, 0, 0);
#else
  const int lane = threadIdx.x & 63;
  *(uint4*)((char*)l + lane * 16) = *(const uint4*)g;
#endif
}

__device__ __forceinline__ float gelu_f(float x) {
  return 0.5f * x * (1.0f + erff(x * 0.70710678118654752f));
}

#define WAITV(N) asm volatile("s_waitcnt vmcnt(" #N ")" ::: "memory")
__device__ __forceinline__ void barrier_nf() {
  asm volatile("s_barrier" ::: "memory");  // raw barrier, no vmcnt drain
}

// Pair-XOR LDS swizzle for BK=32 tiles (64B rows, 128B pair regions).
// Logical (row r, 16B k-chunk q in 0..3) lives at pair p=r>>1,
// chunk c' = (((r&1)<<2)|q) ^ (p&7). Involution applied on the
// global_load_lds SOURCE address and on the ds_read address (rule: swizzle
// both sides or neither). Each lane-octet of a ds_read_b128 then covers 8
// distinct 16B bank-groups -> conflict-free.
__device__ __forceinline__ int swz32(int r, int q) {
  const int p = r >> 1;
  const int c = (((r & 1) << 2) | q) ^ (p & 7);
  return p * 64 + c * 8;  // element offset (f16)
}

// ---------------------------------------------------------------- big GEMM
// C[M,N] = A[M,K] * W[N,K]^T (+bias, epilogue). K = N = 1024.
// 256x256 tile, BK=32, 8 waves (2M x 4N), FOUR LDS buffers (128 KiB),
// depth-3 prefetch: stage(t+3) issued at iteration t; counted vmcnt(8)
// (never 0 until tail); ONE barrier per K-step; setprio around MFMA.
// EPI: 0 = gelu->f16, 1 = plain->f16, 2 = plain->f32, 3 = gelu->f32
// EPI2 >= 0: dual-output mode; blocks with nt >= 4 use W2/bias2/out2.
// T1: bijective XCD swizzle, mt-contiguous chunks, nt fastest (A L2 reuse).
template <int EPI, int EPI2>
__global__ __launch_bounds__(512, 2) void gemm256(
    const f16* __restrict__ A, const f16* __restrict__ W,
    const float* __restrict__ bias, void* __restrict__ out,
    const f16* __restrict__ W2, const float* __restrict__ bias2,
    void* __restrict__ out2, int M) {
  constexpr int K = 1024, N = 1024;
  constexpr int KT = K / 32;               // 32 K-steps
  constexpr int NT = (EPI2 >= 0) ? 8 : 4;  // 256-col tiles (dual: 4 + 4)
  constexpr int NWG = NT * MT256;
  constexpr int CHUNK = NWG / 8;
  __shared__ f16 lds[4][2][256 * 32];  // [buf][A=0/B=1][swizzled]

  // T1: xcd = blockIdx.x % 8 (hardware round-robin).
  const int L = blockIdx.x;
  const int w = (L & 7) * CHUNK + (L >> 3);
  const int mt = w / NT;
  int nt = w % NT;
  const f16* Wp = W;
  const float* bp = bias;
  void* op = out;
  bool second = false;
  if constexpr (EPI2 >= 0) {
    if (nt >= 4) {
      nt -= 4;
      Wp = W2;
      bp = bias2;
      op = out2;
      second = true;
    }
  }

  const int tid = threadIdx.x;
  const int wave = tid >> 6, lane = tid & 63;
  const int m0 = mt * 256, n0 = nt * 256;
  const int wm = (wave >> 2) * 128;  // 2 waves in M
  const int wn = (wave & 3) * 64;    // 4 waves in N
  const int fr = lane & 15, fq = lane >> 4;

  f32x4 acc[8][4];
#pragma unroll
  for (int i = 0; i < 8; ++i)
#pragma unroll
    for (int j = 0; j < 4; ++j) acc[i][j] = (f32x4){0.f, 0.f, 0.f, 0.f};

  // Stage-side source mapping (per 1KB region = 16 rows): lane writes LDS
  // byte lane*16 -> pair p_local = lane>>3, chunk c' = lane&7; it must
  // source logical chunk c = c' ^ p_local -> row offset and k-chunk:
  const int plocal = lane >> 3;
  const int csw = (lane & 7) ^ plocal;
  const int rofs = plocal * 2 + (csw >> 2);  // row within 16-row region
  const int qofs = (csw & 3) * 8;            // element offset within row

  // stage one K-tile: 4 g2l16/thread (2 A regions + 2 B regions per wave)
  auto stage = [&](int t) {
    const int buf = t & 3;
    const int k0 = t * 32;
    f16* Ab = &lds[buf][0][0];
    f16* Bb = &lds[buf][1][0];
#pragma unroll
    for (int la = 0; la < 2; ++la) {
      const int rg = wave * 2 + la;  // 16-row region
      int gm = m0 + rg * 16 + rofs;
      if (gm > M - 1) gm = M - 1;
      g2l16(A + (size_t)gm * K + k0 + qofs, &Ab[rg * 512]);
    }
#pragma unroll
    for (int la = 0; la < 2; ++la) {
      const int rg = wave * 2 + la;
      const int gn = n0 + rg * 16 + rofs;
      g2l16(Wp + (size_t)gn * K + k0 + qofs, &Bb[rg * 512]);
    }
  };

  // one K-step of compute: 12 ds_read_b128 + 32 MFMA
  auto compute = [&](int t) {
    const f16* Ab = &lds[t & 3][0][0];
    const f16* Bb = &lds[t & 3][1][0];
    f16x8 af[8], bf[4];
#pragma unroll
    for (int i = 0; i < 8; ++i)
      af[i] = *(const f16x8*)&Ab[swz32(wm + i * 16 + fr, fq)];
#pragma unroll
    for (int j = 0; j < 4; ++j)
      bf[j] = *(const f16x8*)&Bb[swz32(wn + j * 16 + fr, fq)];
    __builtin_amdgcn_s_setprio(1);
#pragma unroll
    for (int i = 0; i < 8; ++i)
#pragma unroll
      for (int j = 0; j < 4; ++j)
        acc[i][j] = __builtin_amdgcn_mfma_f32_16x16x32_f16(af[i], bf[j],
                                                           acc[i][j], 0, 0, 0);
    __builtin_amdgcn_s_setprio(0);
  };

  // prologue: 3 tiles in flight
  stage(0);
  stage(1);
  stage(2);
  // main loop: wait tile t (vmcnt(8) = tiles t+1,t+2 may stay in flight),
  // barrier (tile t visible to all; prior reads of buf[(t+3)&3] retired),
  // stage t+3, compute t. Single barrier per K-step; no vmcnt(0) drain.
#pragma unroll 4
  for (int t = 0; t < KT - 4; ++t) {
    WAITV(8);
    barrier_nf();
    stage(t + 3);
    compute(t);
  }
  WAITV(8); barrier_nf(); stage(KT - 1); compute(KT - 4);
  WAITV(8); barrier_nf(); compute(KT - 3);
  WAITV(4); barrier_nf(); compute(KT - 2);
  WAITV(0); barrier_nf(); compute(KT - 1);

  // Epilogue. C/D layout: col = lane&15, row = (lane>>4)*4 + reg.
  const bool do_gelu = second ? (EPI2 == 0 || EPI2 == 3) : (EPI == 0 || EPI == 3);
  const bool to_f16 = second ? (EPI2 <= 1) : (EPI <= 1);
  const int row0 = m0 + wm + fq * 4;
  const int col0 = n0 + wn + fr;
#pragma unroll
  for (int j = 0; j < 4; ++j) {
    const int col = col0 + j * 16;
    const float bv = bp[col];
#pragma unroll
    for (int i = 0; i < 8; ++i) {
#pragma unroll
      for (int r = 0; r < 4; ++r) {
        const int row = row0 + i * 16 + r;
        if (row < M) {
          float v = acc[i][j][r] + bv;
          if (do_gelu) v = gelu_f(v);
          if (to_f16)
            ((f16*)op)[(size_t)row * N + col] = (f16)v;
          else
            ((float*)op)[(size_t)row * N + col] = v;
        }
      }
    }
  }
}

// ---------------------------------------------------------------- fp32 -> fp16
__global__ void cvt_f32_f16(const float* __restrict__ in, f16* __restrict__ out,
                            int nchunks) {
  const int i = blockIdx.x * 256 + threadIdx.x;
  if (i >= nchunks) return;
  const float4* p = (const float4*)in + (size_t)i * 2;
  const float4 a = p[0], b = p[1];
  f16x8 o = {(f16)a.x, (f16)a.y, (f16)a.z, (f16)a.w,
             (f16)b.x, (f16)b.y, (f16)b.z, (f16)b.w};
  *((f16x8*)out + i) = o;
}

// ---------------------------------------------------------------- column stats
template <typename T>
__global__ __launch_bounds__(256) void colstats_partial(
    const T* __restrict__ X, float* __restrict__ psum,
    float* __restrict__ psq) {
  const int b = blockIdx.y;
  const int sp = blockIdx.x;
  const int c = threadIdx.x * 4;  // 4 columns per thread
  constexpr int CHUNK = (HW + CSPLIT - 1) / CSPLIT;  // 43
  const int r0 = sp * CHUNK;
  const int r1 = (r0 + CHUNK < HW) ? r0 + CHUNK : HW;

  float s0 = 0.f, s1 = 0.f, s2 = 0.f, s3 = 0.f;
  float q0 = 0.f, q1 = 0.f, q2 = 0.f, q3 = 0.f;
  const T* base = X + ((size_t)b * HW + r0) * DIM + c;
  for (int r = r0; r < r1; ++r) {
    float v0, v1, v2, v3;
    if constexpr (sizeof(T) == 2) {
      const f16x4 v = *(const f16x4*)base;
      v0 = (float)v[0]; v1 = (float)v[1]; v2 = (float)v[2]; v3 = (float)v[3];
    } else {
      const float4 v = *(const float4*)base;
      v0 = v.x; v1 = v.y; v2 = v.z; v3 = v.w;
    }
    s0 += v0; s1 += v1; s2 += v2; s3 += v3;
    q0 += v0 * v0; q1 += v1 * v1; q2 += v2 * v2; q3 += v3 * v3;
    base += DIM;
  }
  const size_t o = ((size_t)sp * NB + b) * DIM + c;
  *(float4*)&psum[o] = make_float4(s0, s1, s2, s3);
  *(float4*)&psq[o] = make_float4(q0, q1, q2, q3);
}

__global__ __launch_bounds__(256) void colstats_final(
    const float* __restrict__ psum, const float* __restrict__ psq,
    float* __restrict__ mean, float* __restrict__ rinv) {
  const int i = blockIdx.x * 256 + threadIdx.x;  // over NB*DIM = 8192
  float s = 0.f, q = 0.f;
  for (int sp = 0; sp < CSPLIT; ++sp) {
    s += psum[(size_t)sp * NB * DIM + i];
    q += psq[(size_t)sp * NB * DIM + i];
  }
  const float m = s * (1.0f / HW);
  const float var = q * (1.0f / HW) - m * m;
  mean[i] = m;
  rinv[i] = rsqrtf(var + 1e-5f);
}

// ---------------------------------------------------------------- k/v small GEMM
__global__ __launch_bounds__(256) void kv_gemm(
    const float* __restrict__ l, const float* __restrict__ lmask,
    const float* __restrict__ wk, const float* __restrict__ bk,
    const float* __restrict__ wv, const float* __restrict__ bv,
    float* __restrict__ Kout, float* __restrict__ Vout) {
  const int b = blockIdx.z;
  const int o0 = blockIdx.x * 64;
  const float* w = blockIdx.y ? wv : wk;
  const float* bb = blockIdx.y ? bv : bk;
  float* out = blockIdx.y ? Vout : Kout;

  __shared__ float wl[64 * 129];
  __shared__ float ll[32 * 129];
  const int tid = threadIdx.x;
  const int o = tid & 63, ng = tid >> 6;  // each thread: 1 o x 8 n
  float acc[8];
#pragma unroll
  for (int j = 0; j < 8; ++j) acc[j] = 0.f;

  for (int kc = 0; kc < LIN; kc += 128) {
    for (int e = tid; e < 64 * 128; e += 256)
      wl[(e >> 7) * 129 + (e & 127)] =
          w[(size_t)(o0 + (e >> 7)) * LIN + kc + (e & 127)];
    for (int e = tid; e < 32 * 128; e += 256)
      ll[(e >> 7) * 129 + (e & 127)] =
          l[(size_t)b * NL * LIN + (size_t)(e >> 7) * LIN + kc + (e & 127)];
    __syncthreads();
    for (int k = 0; k < 128; ++k) {
      const float wv_ = wl[o * 129 + k];
#pragma unroll
      for (int j = 0; j < 8; ++j) acc[j] += wv_ * ll[(ng * 8 + j) * 129 + k];
    }
    __syncthreads();
  }
  const float bval = bb[o0 + o];
#pragma unroll
  for (int j = 0; j < 8; ++j) {
    const int n = ng * 8 + j;
    out[((size_t)b * DIM + o0 + o) * NL + n] =
        (acc[j] + bval) * lmask[b * NL + n];
  }
}

// ---------------------------------------------------------------- attention
__global__ __launch_bounds__(256) void attn_kernel(
    const f16* __restrict__ Q, const float* __restrict__ qmean,
    const float* __restrict__ qrinv, const float* __restrict__ Kk,
    const float* __restrict__ Vv, const float* __restrict__ lmask,
    float* __restrict__ Out) {
  const int b = blockIdx.z, h = blockIdx.y;
  __shared__ float ks[128 * NL], vs[128 * NL], qm[128], qr[128], bs[NL];
  const int tid = threadIdx.x;
  const float* kbase = Kk + ((size_t)b * DIM + h * 128) * NL;
  const float* vbase = Vv + ((size_t)b * DIM + h * 128) * NL;
  for (int i = tid; i < 128 * NL; i += 256) {
    ks[i] = kbase[i];
    vs[i] = vbase[i];
  }
  if (tid < 128) {
    qm[tid] = qmean[b * DIM + h * 128 + tid];
    qr[tid] = qrinv[b * DIM + h * 128 + tid];
  }
  if (tid < NL) bs[tid] = (lmask[b * NL + tid] - 1.0f) * 10000.0f;
  __syncthreads();

  const int mloc = blockIdx.x * 256 + tid;
  if (mloc >= HW) return;
  const size_t m = (size_t)b * HW + mloc;
  const f16* qrow = Q + m * DIM + h * 128;

  float sc[32];
#pragma unroll
  for (int n = 0; n < 32; ++n) sc[n] = 0.f;

  for (int d8 = 0; d8 < 16; ++d8) {
    const f16x8 qv = *(const f16x8*)(qrow + d8 * 8);
#pragma unroll
    for (int j = 0; j < 8; ++j) {
      const int d = d8 * 8 + j;
      const float qd = ((float)qv[j] - qm[d]) * qr[d];
      const float4* kr = (const float4*)&ks[d * 32];
#pragma unroll
      for (int n4 = 0; n4 < 8; ++n4) {
        const float4 kk = kr[n4];
        sc[n4 * 4 + 0] += qd * kk.x;
        sc[n4 * 4 + 1] += qd * kk.y;
        sc[n4 * 4 + 2] += qd * kk.z;
        sc[n4 * 4 + 3] += qd * kk.w;
      }
    }
  }
  float mx = -1e30f;
#pragma unroll
  for (int n = 0; n < 32; ++n) {
    sc[n] = sc[n] * 0.03125f + bs[n];  // * KC^-0.5 then masked bias
    mx = fmaxf(mx, sc[n]);
  }
  float sum = 0.f;
#pragma unroll
  for (int n = 0; n < 32; ++n) {
    sc[n] = __expf(sc[n] - mx);
    sum += sc[n];
  }
  const float rs = 1.0f / sum;

  float* orow = Out + m * DIM + h * 128;
  for (int dv8 = 0; dv8 < 16; ++dv8) {
    float ov[8];
#pragma unroll
    for (int j = 0; j < 8; ++j) {
      const float4* vr = (const float4*)&vs[(dv8 * 8 + j) * 32];
      float a = 0.f;
#pragma unroll
      for (int n4 = 0; n4 < 8; ++n4) {
        const float4 vv = vr[n4];
        a += sc[n4 * 4 + 0] * vv.x + sc[n4 * 4 + 1] * vv.y +
             sc[n4 * 4 + 2] * vv.z + sc[n4 * 4 + 3] * vv.w;
      }
      ov[j] = a * rs;
    }
    float4* op = (float4*)(orow + dv8 * 8);
    op[0] = make_float4(ov[0], ov[1], ov[2], ov[3]);
    op[1] = make_float4(ov[4], ov[5], ov[6], ov[7]);
  }
}

// ---------------------------------------------------------------- center (attn - colmean) -> f16
__global__ void center_kernel(const float* __restrict__ X,
                              const float* __restrict__ mean,
                              f16* __restrict__ out, int nchunks) {
  const int i = blockIdx.x * 256 + threadIdx.x;
  if (i >= nchunks) return;
  const size_t e = (size_t)i * 8;
  const int mrow = (int)(e >> 10);
  const int o = (int)(e & 1023);
  const int b = mrow / HW;
  const float4* p = (const float4*)(X + e);
  const float4 a = p[0], c = p[1];
  const float* mn = mean + b * DIM + o;
  f16x8 r = {(f16)(a.x - mn[0]), (f16)(a.y - mn[1]), (f16)(a.z - mn[2]),
             (f16)(a.w - mn[3]), (f16)(c.x - mn[4]), (f16)(c.y - mn[5]),
             (f16)(c.z - mn[6]), (f16)(c.w - mn[7])};
  *((f16x8*)out + i) = r;
}

// ---------------------------------------------------------------- fuse: mm = vis * inorm(lang_pre)
__global__ void fuse_kernel(const f16* __restrict__ vis,
                            const float* __restrict__ lang,
                            const float* __restrict__ mean,
                            const float* __restrict__ rinv,
                            f16* __restrict__ out, int nchunks) {
  const int i = blockIdx.x * 256 + threadIdx.x;
  if (i >= nchunks) return;
  const size_t e = (size_t)i * 8;
  const int mrow = (int)(e >> 10);
  const int o = (int)(e & 1023);
  const int b = mrow / HW;
  const f16x8 v = *((const f16x8*)vis + i);
  const float4* p = (const float4*)(lang + e);
  const float4 a = p[0], c = p[1];
  const float lv[8] = {a.x, a.y, a.z, a.w, c.x, c.y, c.z, c.w};
  const float* mn = mean + b * DIM + o;
  const float* ri = rinv + b * DIM + o;
  f16x8 r;
#pragma unroll
  for (int j = 0; j < 8; ++j)
    r[j] = (f16)((float)v[j] * ((lv[j] - mn[j]) * ri[j]));
  *((f16x8*)out + i) = r;
}

// ---------------------------------------------------------------- launch
extern "C" void kernel_launch(void* const* d_in, const int* in_sizes, int n_in,
                              void* d_out, int out_size, void* d_ws,
                              size_t ws_size, hipStream_t stream) {
  const float* x     = (const float*)d_in[0];
  const float* l     = (const float*)d_in[1];
  const float* lmask = (const float*)d_in[2];
  const float* vis_w = (const float*)d_in[3];
  const float* vis_b = (const float*)d_in[4];
  const float* fq_w  = (const float*)d_in[5];
  const float* fq_b  = (const float*)d_in[6];
  const float* fk_w  = (const float*)d_in[7];
  const float* fk_b  = (const float*)d_in[8];
  const float* fv_w  = (const float*)d_in[9];
  const float* fv_b  = (const float*)d_in[10];
  const float* W_w   = (const float*)d_in[11];
  const float* W_b   = (const float*)d_in[12];
  const float* pm_w  = (const float*)d_in[13];
  const float* pm_b  = (const float*)d_in[14];

  char* ws = (char*)d_ws;
  const size_t SB = (size_t)MTOT * DIM * 2;  // one f16 [M,1024] buffer
  f16* Ah = (f16*)(ws);                      // x_f16 -> centered attn -> mm
  f16* Bh = (f16*)(ws + SB);                 // vis
  f16* Ch = (f16*)(ws + 2 * SB);             // q (f16)
  float* Df = (float*)(ws + 3 * SB);         // attn f32 -> lang_pre f32 (2*SB bytes)
  char* wsp = ws + 5 * SB;
  f16* vis_wh = (f16*)(wsp);
  f16* fq_wh  = (f16*)(wsp + (1 << 21));
  f16* W_wh   = (f16*)(wsp + 2 * (1 << 21));
  f16* pm_wh  = (f16*)(wsp + 3 * (1 << 21));
  float* Kout = (float*)(wsp + 4 * (1 << 21));
  float* Vout = (float*)(wsp + 4 * (1 << 21) + (1 << 20));
  float* st   = (float*)(wsp + 4 * (1 << 21) + 2 * (1 << 20));
  float* qmean = st;
  float* qrinv = st + 8192;
  float* amean = st + 16384;
  float* arinv = st + 24576;
  float* lmean = st + 32768;
  float* lrinv = st + 40960;
  float* psum  = (float*)(wsp + 4 * (1 << 21) + 3 * (1 << 20));  // CSPLIT*NB*DIM
  float* psq   = psum + (size_t)CSPLIT * NB * DIM;

  const int NCH_BIG = MTOT * DIM / 8;  // 5,607,424 chunks of 8
  const int NCH_W = DIM * DIM / 8;     // 131,072

  cvt_f32_f16<<<(NCH_BIG + 255) / 256, 256, 0, stream>>>(x, Ah, NCH_BIG);
  cvt_f32_f16<<<(NCH_W + 255) / 256, 256, 0, stream>>>(vis_w, vis_wh, NCH_W);
  cvt_f32_f16<<<(NCH_W + 255) / 256, 256, 0, stream>>>(fq_w, fq_wh, NCH_W);
  cvt_f32_f16<<<(NCH_W + 255) / 256, 256, 0, stream>>>(W_w, W_wh, NCH_W);
  cvt_f32_f16<<<(NCH_W + 255) / 256, 256, 0, stream>>>(pm_w, pm_wh, NCH_W);

  kv_gemm<<<dim3(16, 2, 8), 256, 0, stream>>>(l, lmask, fk_w, fk_b, fv_w, fv_b,
                                              Kout, Vout);

  // vis + q fused: one pass over A, 8 col-tiles (4 vis/gelu, 4 fq/plain).
  gemm256<0, 1><<<8 * MT256, 512, 0, stream>>>(
      Ah, vis_wh, vis_b, Bh, fq_wh, fq_b, Ch, MTOT);

  colstats_partial<f16><<<dim3(CSPLIT, NB), 256, 0, stream>>>(Ch, psum, psq);
  colstats_final<<<32, 256, 0, stream>>>(psum, psq, qmean, qrinv);

  attn_kernel<<<dim3((HW + 255) / 256, 8, 8), 256, 0, stream>>>(
      Ch, qmean, qrinv, Kout, Vout, lmask, Df);

  colstats_partial<float><<<dim3(CSPLIT, NB), 256, 0, stream>>>(Df, psum, psq);
  colstats_final<<<32, 256, 0, stream>>>(psum, psq, amean, arinv);
  center_kernel<<<(NCH_BIG + 255) / 256, 256, 0, stream>>>(Df, amean, Ah,
                                                           NCH_BIG);

  gemm256<2, -1><<<4 * MT256, 512, 0, stream>>>(
      Ah, W_wh, W_b, Df, nullptr, nullptr, nullptr, MTOT);  // lang_pre f32
  colstats_partial<float><<<dim3(CSPLIT, NB), 256, 0, stream>>>(Df, psum, psq);
  colstats_final<<<32, 256, 0, stream>>>(psum, psq, lmean, lrinv);
  fuse_kernel<<<(NCH_BIG + 255) / 256, 256, 0, stream>>>(Bh, Df, lmean, lrinv,
                                                         Ah, NCH_BIG);

  gemm256<3, -1><<<4 * MT256, 512, 0, stream>>>(
      Ah, pm_wh, pm_b, d_out, nullptr, nullptr, nullptr, MTOT);  // output
}